// Round 19
// baseline (676.615 us; speedup 1.0000x reference)
//
#include <hip/hip_runtime.h>
#include <hip/hip_bf16.h>
#include <stdint.h>
#include <algorithm>

#define BB  32
#define LL  512
#define NCI 21
#define DD  512
#define NH  8
#define EHH 64
#define NDFF 2048
#define NM  32
#define NEL 3
#define NCC 10

struct Modes { int v[NM]; };

typedef __bf16 bf16x8 __attribute__((ext_vector_type(8)));
typedef float f32x4 __attribute__((ext_vector_type(4)));
typedef float f32x16 __attribute__((ext_vector_type(16)));

// A&S 7.1.26 erf, |eps| <= 1.5e-7, branchless
__device__ __forceinline__ float erf_poly(float x) {
    float ax = fabsf(x);
    float t = 1.0f / fmaf(0.3275911f, ax, 1.0f);
    float y = t * fmaf(t, fmaf(t, fmaf(t, fmaf(t, 1.061405429f, -1.453152027f),
                                       1.421413741f), -0.284496736f), 0.254829592f);
    float r = 1.0f - y * __expf(-ax * ax);
    return copysignf(r, x);
}

__device__ __forceinline__ float gelu_f(float x) {
    return 0.5f * x * (1.0f + erf_poly(x * 0.7071067811865475f));
}

__device__ __forceinline__ float bf2f(uint16_t u) {
    union { uint32_t u32; float f; } c;
    c.u32 = (uint32_t)u << 16;
    return c.f;
}

__device__ __forceinline__ void gload_lds16(const void* g, void* l) {
    __builtin_amdgcn_global_load_lds((const __attribute__((address_space(1))) void*)g,
                                     (__attribute__((address_space(3))) void*)l, 16, 0, 0);
}

// ---------------- combined tables: PE (512 rows), T (64 rows), Sk (64 rows) --------------
__global__ void k_tabs(float* __restrict__ PE, __hip_bfloat16* __restrict__ Tb,
                       __hip_bfloat16* __restrict__ Sk, Modes md) {
    int bid = blockIdx.x;
    const float w0 = 6.283185307179586f / 512.0f;
    if (bid < 512) {
        int l = bid;
        for (int d = threadIdx.x; d < DD; d += 256) {
            int a = d & ~1;
            float freq = expf((float)a * (-9.210340371976184f / 512.0f));
            float v = (float)l * freq;
            PE[l * DD + d] = (d & 1) ? cosf(v) : sinf(v);
        }
    } else if (bid < 576) {
        int r = bid - 512, m = r >> 1, im = md.v[m];
        for (int l = threadIdx.x; l < LL; l += 256) {
            int red = (im * l) & 511;
            float ang = w0 * (float)red;
            Tb[r * 512 + l] = __float2bfloat16((r & 1) ? sinf(ang) : cosf(ang));
        }
    } else {
        int k = bid - 576, m = k >> 1;
        for (int l = threadIdx.x; l < LL; l += 256) {
            int red = (m * l) & 511;
            float ang = w0 * (float)red;
            float v;
            if ((k & 1) == 0) v = cosf(ang) * (m == 0 ? (1.0f / 512.0f) : (2.0f / 512.0f));
            else              v = -sinf(ang) * (2.0f / 512.0f);
            Sk[k * 512 + l] = __float2bfloat16(v);
        }
    }
}

// ---------------- embedding: conv1d(k=3, circular) + PE -> bf16 Xb AND XT[b][d][l] -------
__global__ __launch_bounds__(256) void k_embed(const float* __restrict__ xe,
        const float* __restrict__ tw, const float* __restrict__ PE,
        __hip_bfloat16* __restrict__ Xb, __hip_bfloat16* __restrict__ XT) {
    int lc = blockIdx.x, dh = blockIdx.y, b = blockIdx.z;
    int t = threadIdx.x;
    int d = dh * 256 + t;
    __shared__ float s_xe[34][NCI];
    int l0 = lc * 32;
    for (int i = t; i < 34 * NCI; i += 256) {
        int r = i / NCI, c = i % NCI;
        int ls = (l0 - 1 + r + LL) & (LL - 1);
        s_xe[r][c] = xe[(b * LL + ls) * NCI + c];
    }
    float twr[63];
    #pragma unroll
    for (int kc = 0; kc < 63; ++kc) twr[kc] = tw[kc * DD + d];
    __syncthreads();
    __hip_bfloat16* xtp = XT + ((size_t)b * DD + d) * LL + l0;
    #pragma unroll
    for (int c8 = 0; c8 < 4; ++c8) {
        bf16x8 xv;
        #pragma unroll
        for (int j = 0; j < 8; ++j) {
            int li = c8 * 8 + j;
            int l = l0 + li;
            float acc = 0.f;
            #pragma unroll
            for (int k = 0; k < 3; ++k)
                #pragma unroll
                for (int c = 0; c < NCI; ++c)
                    acc = fmaf(s_xe[li + k][c], twr[k * NCI + c], acc);
            float r = acc + PE[l * DD + d];
            __hip_bfloat16 rb = __float2bfloat16(r);
            Xb[((size_t)(b * LL + l)) * DD + d] = rb;
            xv[j] = *(__bf16*)&rb;
        }
        *(bf16x8*)(xtp + c8 * 8) = xv;
    }
}

// ---------------- ALL weight converts in one launch (1-D segment decode) -----------------
__global__ void k_wtall(const float* __restrict__ Wq, const float* __restrict__ W1,
                        const float* __restrict__ W2, const float* __restrict__ Wo,
                        __hip_bfloat16* __restrict__ WTq, __hip_bfloat16* __restrict__ WT1,
                        __hip_bfloat16* __restrict__ WT2, __hip_bfloat16* __restrict__ WT3) {
    int id = blockIdx.x;
    const float* W; __hip_bfloat16* WT; int K, N, gx, li, r;
    if (id < 768)        { li = id / 256; r = id % 256;  W = Wq; WT = WTq; K = 512;  N = 512;  gx = 16; }
    else if (id < 3840)  { id -= 768;  li = id / 1024; r = id % 1024; W = W1; WT = WT1; K = 512;  N = 2048; gx = 64; }
    else if (id < 6912)  { id -= 3840; li = id / 1024; r = id % 1024; W = W2; WT = WT2; K = 2048; N = 512;  gx = 16; }
    else                 { id -= 6912; li = id / 256;  r = id % 256;  W = Wo; WT = WT3; K = 512;  N = 512;  gx = 16; }
    int bx = r % gx, by = r / gx;
    size_t loff = (size_t)li * K * N;
    W += loff; WT += loff;
    __shared__ float s[32][33];
    int t = threadIdx.x;
    int rr = t >> 5, c = t & 31;
    #pragma unroll
    for (int i = 0; i < 4; ++i)
        s[rr + i * 8][c] = W[(size_t)(by * 32 + rr + i * 8) * N + bx * 32 + c];
    __syncthreads();
    #pragma unroll
    for (int i = 0; i < 4; ++i) {
        int n = bx * 32 + rr + i * 8;
        WT[(size_t)n * K + by * 32 + c] = __float2bfloat16(s[c][rr + i * 8]);
    }
}

// ---------------- fourier weight transpose -> packed bf16 pairs WM3[li][hm][e][o] --------
__global__ void k_wfm(const float* __restrict__ fwr, const float* __restrict__ fwi,
                      uint32_t* __restrict__ WM3) {
    int li = blockIdx.y;
    int blk = blockIdx.x;        // h*64 + e
    int h = blk >> 6, e = blk & 63;
    int t = threadIdx.x;
    __shared__ uint32_t s[32][65];
    const float* br = fwr + (((size_t)(li * NH + h) * EHH + e) * EHH) * NM;
    const float* bi = fwi + (((size_t)(li * NH + h) * EHH + e) * EHH) * NM;
    for (int i = t; i < 2048; i += 256) {
        int o = i >> 5, m = i & 31;
        union { __hip_bfloat16 h2[2]; uint32_t u; } pk;
        pk.h2[0] = __float2bfloat16(br[i]);
        pk.h2[1] = __float2bfloat16(bi[i]);
        s[m][o] = pk.u;
    }
    __syncthreads();
    uint32_t* WM = WM3 + (size_t)li * (NH * NM * EHH * EHH);
    int mr = t >> 6, o = t & 63;
    for (int m = mr; m < 32; m += 4)
        WM[((size_t)(h * 32 + m)) * 4096 + e * 64 + o] = s[m][o];
}

// ---------------- TX[b] = T[64x512] @ XT[b], 64-col tiles (256 blocks, full GPU) ---------
__global__ __launch_bounds__(256) void k_tx(const __hip_bfloat16* __restrict__ Tb,
        const __hip_bfloat16* __restrict__ XT, __hip_bfloat16* __restrict__ TX) {
    __shared__ __hip_bfloat16 Ts[64 * 32];
    __shared__ __hip_bfloat16 Xs[64 * 32];
    int b = blockIdx.x, n0 = blockIdx.y * 64;
    int t = threadIdx.x, w = t >> 6, ln = t & 63;
    const __hip_bfloat16* xb = XT + (size_t)b * DD * LL;
    int srow = t >> 2, sq = t & 3;
    f32x4 acc[4] = {};
    for (int k0 = 0; k0 < 512; k0 += 32) {
        gload_lds16(Tb + srow * 512 + k0 + sq * 8, (char*)Ts + w * 1024);
        gload_lds16(xb + (size_t)(n0 + srow) * LL + k0 + sq * 8, (char*)Xs + w * 1024);
        __syncthreads();
        int lr = ln & 15, kc = (ln >> 4) * 8;
        bf16x8 af[4], bfr;
        #pragma unroll
        for (int mi = 0; mi < 4; ++mi)
            af[mi] = *(const bf16x8*)&Ts[(mi * 16 + lr) * 32 + kc];
        bfr = *(const bf16x8*)&Xs[(w * 16 + lr) * 32 + kc];
        #pragma unroll
        for (int mi = 0; mi < 4; ++mi)
            acc[mi] = __builtin_amdgcn_mfma_f32_16x16x32_bf16(af[mi], bfr, acc[mi], 0, 0, 0);
        __syncthreads();
    }
    int rb = (ln >> 4) * 4, cb = ln & 15;
    #pragma unroll
    for (int mi = 0; mi < 4; ++mi)
        #pragma unroll
        for (int j = 0; j < 4; ++j) {
            int m = mi * 16 + rb + j;
            int col = n0 + w * 16 + cb;
            TX[(size_t)(b * 64 + m) * 512 + col] = __float2bfloat16(acc[mi][j]);
        }
}

// ---------------- SW = Sk @ WoT^T (batched layers via blockIdx.y) -> SWT[dc][k] ----------
__global__ __launch_bounds__(256) void k_swt(const __hip_bfloat16* __restrict__ Sk,
        const __hip_bfloat16* __restrict__ WT3, __hip_bfloat16* __restrict__ SW3) {
    int li = blockIdx.y;
    const __hip_bfloat16* WT = WT3 + (size_t)li * DD * DD;
    __hip_bfloat16* SWT = SW3 + (size_t)li * DD * 64;
    __shared__ __hip_bfloat16 Ts[64 * 32];
    __shared__ __hip_bfloat16 Xs[128 * 32];
    int n0 = blockIdx.x * 128;
    int t = threadIdx.x, w = t >> 6, ln = t & 63;
    f32x4 acc[4][2] = {};
    for (int k0 = 0; k0 < 512; k0 += 32) {
        {
            int row = w * 16 + (ln >> 2), q = ln & 3;
            gload_lds16(Sk + row * 512 + k0 + q * 8, (char*)Ts + w * 1024);
        }
        #pragma unroll
        for (int i = 0; i < 2; ++i) {
            int s = i * 256 + t;
            int row = s >> 2, q = s & 3;
            gload_lds16(WT + (size_t)(n0 + row) * 512 + k0 + q * 8,
                        (char*)Xs + i * 4096 + w * 1024);
        }
        __syncthreads();
        int lr = ln & 15, kc = (ln >> 4) * 8;
        bf16x8 af[4], bfr[2];
        #pragma unroll
        for (int mi = 0; mi < 4; ++mi)
            af[mi] = *(const bf16x8*)&Ts[(mi * 16 + lr) * 32 + kc];
        #pragma unroll
        for (int ni = 0; ni < 2; ++ni)
            bfr[ni] = *(const bf16x8*)&Xs[(w * 32 + ni * 16 + lr) * 32 + kc];
        #pragma unroll
        for (int mi = 0; mi < 4; ++mi)
            #pragma unroll
            for (int ni = 0; ni < 2; ++ni)
                acc[mi][ni] = __builtin_amdgcn_mfma_f32_16x16x32_bf16(
                    af[mi], bfr[ni], acc[mi][ni], 0, 0, 0);
        __syncthreads();
    }
    int rb = (ln >> 4) * 4, cb = ln & 15;
    #pragma unroll
    for (int mi = 0; mi < 4; ++mi)
        #pragma unroll
        for (int ni = 0; ni < 2; ++ni)
            #pragma unroll
            for (int j = 0; j < 4; ++j) {
                int k = mi * 16 + rb + j;
                int col = n0 + w * 32 + ni * 16 + cb;   // dc
                SWT[(size_t)col * 64 + k] = __float2bfloat16(acc[mi][ni][j]);
            }
}

// ---------------- XG = TX @ Wq, 64x64 tiles (256 blocks), scatter to [hm][e*32+b] --------
__global__ __launch_bounds__(256) void k_xg(const __hip_bfloat16* __restrict__ A,
        const __hip_bfloat16* __restrict__ Bt, const float* __restrict__ bq,
        float* __restrict__ XGr, float* __restrict__ XGi, Modes md) {
    __shared__ __hip_bfloat16 As[64 * 32];
    __shared__ __hip_bfloat16 Bs[64 * 32];
    int t = threadIdx.x;
    int m0 = blockIdx.x * 64, n0 = blockIdx.y * 64;
    int w = t >> 6, ln = t & 63;
    int wr = w >> 1, wc = w & 1;
    int srow = t >> 2, sq = t & 3;
    const int K = 512;
    f32x4 acc[2][2] = {};
    for (int k0 = 0; k0 < K; k0 += 32) {
        gload_lds16(A + (size_t)(m0 + srow) * K + k0 + sq * 8, (char*)As + w * 1024);
        gload_lds16(Bt + (size_t)(n0 + srow) * K + k0 + sq * 8, (char*)Bs + w * 1024);
        __syncthreads();
        bf16x8 af[2], bfr[2];
        int lr = ln & 15, kc = (ln >> 4) * 8;
        #pragma unroll
        for (int mi = 0; mi < 2; ++mi)
            af[mi] = *(const bf16x8*)&As[(wr * 32 + mi * 16 + lr) * 32 + kc];
        #pragma unroll
        for (int ni = 0; ni < 2; ++ni)
            bfr[ni] = *(const bf16x8*)&Bs[(wc * 32 + ni * 16 + lr) * 32 + kc];
        #pragma unroll
        for (int mi = 0; mi < 2; ++mi)
            #pragma unroll
            for (int ni = 0; ni < 2; ++ni)
                acc[mi][ni] = __builtin_amdgcn_mfma_f32_16x16x32_bf16(
                    af[mi], bfr[ni], acc[mi][ni], 0, 0, 0);
        __syncthreads();
    }
    int rb = (ln >> 4) * 4, cb = ln & 15;
    #pragma unroll
    for (int mi = 0; mi < 2; ++mi) {
        #pragma unroll
        for (int ni = 0; ni < 2; ++ni) {
            int col = n0 + wc * 32 + ni * 16 + cb;
            int h = col >> 6, e = col & 63;
            #pragma unroll
            for (int j = 0; j < 4; ++j) {
                int row = m0 + wr * 32 + mi * 16 + rb + j;
                int b = row >> 6, r = row & 63, m = r >> 1;
                float v = acc[mi][ni][j];
                int off = (h * 32 + m) * 2048 + e * 32 + b;
                if ((r & 1) == 0)
                    XGr[off] = v + (md.v[m] == 0 ? 512.f * bq[col] : 0.f);
                else
                    XGi[off] = -v;
            }
        }
    }
}

// ---------------- FFN GEMM: 128x128, BK=32, 3-buf counted-vmcnt, 3 blk/CU ----------------
// 32x32x16 MFMA (2x2 per wave): halves MFMA instruction count vs 16x16x32 at same
// operand bytes. A/B frag: row=lane&31, k=(lane>>5)*8; C/D: col=lane&31,
// row=(reg&3)+8*(reg>>2)+4*(lane>>5) (guide-verified m74/m101).
// LDS XOR swizzle slot = k8 ^ ((row>>1)&3). EPI 1: gelu bf16; EPI 3: plain bf16.
template<int EPI>
__global__ __launch_bounds__(256, 3) void k_ffn(const __hip_bfloat16* __restrict__ A,
        const __hip_bfloat16* __restrict__ Bt, __hip_bfloat16* __restrict__ Cb,
        int M, int N, int K) {
    constexpr int TILE = 256 * 32;             // (128A+128B) x 32k elements = 16 KB
    __shared__ __hip_bfloat16 lds[3 * TILE];   // 48 KB -> 3 blocks/CU
    int t = threadIdx.x, w = t >> 6, ln = t & 63;
    int wr = w >> 1, wc = w & 1;
    int r32 = ln & 31, g2 = ln >> 5;           // row-in-32-tile, k-group
    int m0 = blockIdx.x * 128, n0 = blockIdx.y * 128;
    f32x16 acc[2][2] = {};
    int NT = K / 32;

    auto STAGE = [&](int buf, int kt) {
        int kb = kt * 32;
        char* ldsA = (char*)(lds + buf * TILE);    // A: 128 rows x 64 B
        char* ldsB = ldsA + 128 * 64;
        #pragma unroll
        for (int i = 0; i < 2; ++i) {
            int c = i * 256 + t;
            int row = c >> 2, q = c & 3;
            int slot = q ^ ((row >> 1) & 3);       // pre-swizzled SOURCE, linear dest
            gload_lds16(A + (size_t)(m0 + row) * K + kb + slot * 8,
                        ldsA + (i * 256 + w * 64) * 16);
        }
        #pragma unroll
        for (int i = 0; i < 2; ++i) {
            int c = i * 256 + t;
            int row = c >> 2, q = c & 3;
            int slot = q ^ ((row >> 1) & 3);
            gload_lds16(Bt + (size_t)(n0 + row) * K + kb + slot * 8,
                        ldsB + (i * 256 + w * 64) * 16);
        }
    };

    STAGE(0, 0);
    STAGE(1, 1);
    for (int kt = 0; kt < NT; ++kt) {
        if (kt + 1 < NT) asm volatile("s_waitcnt vmcnt(4)" ::: "memory");
        else             asm volatile("s_waitcnt vmcnt(0)" ::: "memory");
        __builtin_amdgcn_sched_barrier(0);
        __builtin_amdgcn_s_barrier();          // all waves: tile kt ready, kt-1 reads done
        __builtin_amdgcn_sched_barrier(0);
        if (kt + 2 < NT) STAGE((kt + 2) % 3, kt + 2);
        const __hip_bfloat16* As = lds + (kt % 3) * TILE;
        const __hip_bfloat16* Bs = As + 128 * 32;
        #pragma unroll
        for (int kk = 0; kk < 2; ++kk) {
            bf16x8 a[2], b[2];
            #pragma unroll
            for (int ti = 0; ti < 2; ++ti) {
                int row = wr * 64 + ti * 32 + r32;
                int s = (kk * 2 + g2) ^ ((row >> 1) & 3);   // swizzled READ
                a[ti] = *(const bf16x8*)&As[row * 32 + s * 8];
            }
            #pragma unroll
            for (int tj = 0; tj < 2; ++tj) {
                int row = wc * 64 + tj * 32 + r32;
                int s = (kk * 2 + g2) ^ ((row >> 1) & 3);
                b[tj] = *(const bf16x8*)&Bs[row * 32 + s * 8];
            }
            __builtin_amdgcn_s_setprio(1);
            #pragma unroll
            for (int ti = 0; ti < 2; ++ti)
                #pragma unroll
                for (int tj = 0; tj < 2; ++tj)
                    acc[ti][tj] = __builtin_amdgcn_mfma_f32_32x32x16_bf16(
                        a[ti], b[tj], acc[ti][tj], 0, 0, 0);
            __builtin_amdgcn_s_setprio(0);
        }
    }
    // epilogue: C/D layout col=lane&31, row=(r&3)+8*(r>>2)+4*g2
    #pragma unroll
    for (int ti = 0; ti < 2; ++ti) {
        #pragma unroll
        for (int tj = 0; tj < 2; ++tj) {
            int col = n0 + wc * 64 + tj * 32 + r32;
            int rowbase = m0 + wr * 64 + ti * 32 + 4 * g2;
            #pragma unroll
            for (int r = 0; r < 16; ++r) {
                int row = rowbase + (r & 3) + 8 * (r >> 2);
                float v = acc[ti][tj][r];
                size_t off = (size_t)row * N + col;
                if (EPI == 1) Cb[off] = __float2bfloat16(gelu_f(v));
                else Cb[off] = __float2bfloat16(v);
            }
        }
    }
}

// ---------------- og: per (h,m) complex GEMM (packed bf16 W) -> OGT[b][he][k] bf16 -------
__global__ __launch_bounds__(256) void k_og(const float* __restrict__ XGr,
        const float* __restrict__ XGi, const uint32_t* __restrict__ WM,
        __hip_bfloat16* __restrict__ OGT) {
    int hm = blockIdx.x;      // h*32+m
    int t = threadIdx.x;
    __shared__ uint32_t sw[4096];
    __shared__ float sxr[2048], sxi[2048];
    const uint32_t* w = WM + (size_t)hm * 4096;
    for (int i = t; i < 4096; i += 256) sw[i] = w[i];
    const float* xr = XGr + hm * 2048;
    const float* xi = XGi + hm * 2048;
    for (int i = t; i < 2048; i += 256) { sxr[i] = xr[i]; sxi[i] = xi[i]; }
    __syncthreads();
    int b = t >> 3, o0 = (t & 7) * 8;
    float ar[8] = {}, ai[8] = {};
    for (int e = 0; e < 64; ++e) {
        float xrv = sxr[e * 32 + b], xiv = sxi[e * 32 + b];
        #pragma unroll
        for (int j = 0; j < 8; ++j) {
            uint32_t wv = sw[e * 64 + o0 + j];
            float wrv = bf2f((uint16_t)(wv & 0xffffu));
            float wiv = bf2f((uint16_t)(wv >> 16));
            ar[j] = fmaf(xrv, wrv, fmaf(-xiv, wiv, ar[j]));
            ai[j] = fmaf(xrv, wiv, fmaf( xiv, wrv, ai[j]));
        }
    }
    int h = hm >> 5, m = hm & 31;
    __hip_bfloat16* og = OGT + (size_t)b * (512 * 64);
    #pragma unroll
    for (int j = 0; j < 8; ++j) {
        int he = h * 64 + o0 + j;
        union { __hip_bfloat16 h2[2]; uint32_t u; } pk;
        pk.h2[0] = __float2bfloat16(ar[j]);
        pk.h2[1] = __float2bfloat16(ai[j]);
        *(uint32_t*)&og[he * 64 + 2 * m] = pk.u;
    }
}

// ---------------- new_x[b][he][dc] = OGT[b](512he x 64k) @ SWT^T + bo -> bf16 ------------
__global__ __launch_bounds__(256) void k_nx(const __hip_bfloat16* __restrict__ OGT,
        const __hip_bfloat16* __restrict__ SWT, const float* __restrict__ bo,
        __hip_bfloat16* __restrict__ Cb) {
    __shared__ __hip_bfloat16 As[128 * 32];
    __shared__ __hip_bfloat16 Bs[128 * 32];
    int t = threadIdx.x;
    int m0 = blockIdx.x * 128, n0 = blockIdx.y * 128, b = blockIdx.z;
    int w = t >> 6, ln = t & 63;
    int wr = w >> 1, wc = w & 1;
    const __hip_bfloat16* ab = OGT + (size_t)b * 512 * 64;
    f32x4 acc[4][4] = {};
    for (int k0 = 0; k0 < 64; k0 += 32) {
        #pragma unroll
        for (int i = 0; i < 2; ++i) {
            int s = i * 256 + t;
            int row = s >> 2, q = s & 3;
            gload_lds16(ab + (size_t)(m0 + row) * 64 + k0 + q * 8,
                        (char*)As + i * 4096 + w * 1024);
            gload_lds16(SWT + (size_t)(n0 + row) * 64 + k0 + q * 8,
                        (char*)Bs + i * 4096 + w * 1024);
        }
        __syncthreads();
        bf16x8 af[4], bfr[4];
        int lr = ln & 15, kc = (ln >> 4) * 8;
        #pragma unroll
        for (int mi = 0; mi < 4; ++mi)
            af[mi] = *(const bf16x8*)&As[(wr * 64 + mi * 16 + lr) * 32 + kc];
        #pragma unroll
        for (int ni = 0; ni < 4; ++ni)
            bfr[ni] = *(const bf16x8*)&Bs[(wc * 64 + ni * 16 + lr) * 32 + kc];
        #pragma unroll
        for (int mi = 0; mi < 4; ++mi)
            #pragma unroll
            for (int ni = 0; ni < 4; ++ni)
                acc[mi][ni] = __builtin_amdgcn_mfma_f32_16x16x32_bf16(
                    af[mi], bfr[ni], acc[mi][ni], 0, 0, 0);
        __syncthreads();
    }
    int rb = (ln >> 4) * 4, cb = ln & 15;
    #pragma unroll
    for (int mi = 0; mi < 4; ++mi) {
        #pragma unroll
        for (int ni = 0; ni < 4; ++ni) {
            int col = n0 + wc * 64 + ni * 16 + cb;
            int he = m0 + wr * 64 + mi * 16 + rb;
            float bv = bo[col];
            #pragma unroll
            for (int j = 0; j < 4; ++j)
                Cb[((size_t)b * 512 + he + j) * 512 + col] =
                    __float2bfloat16(acc[mi][ni][j] + bv);
        }
    }
}

// ---------------- s = P + Q; out = s - movavg25(s) -> bf16 (+ optional XT write) ---------
template<bool WRITE_XT>
__global__ void k_add_decomp(const __hip_bfloat16* __restrict__ P,
                             const __hip_bfloat16* __restrict__ Q,
                             __hip_bfloat16* __restrict__ Outb,
                             __hip_bfloat16* __restrict__ XT) {
    int b = blockIdx.x >> 3;
    int l0 = (blockIdx.x & 7) * 64;
    int d = threadIdx.x;
    const __hip_bfloat16* p = P + (size_t)b * LL * DD + d;
    const __hip_bfloat16* q = Q + (size_t)b * LL * DD + d;
    __hip_bfloat16* ob = Outb + (size_t)b * LL * DD + d;
    __hip_bfloat16* xtp = WRITE_XT ? (XT + ((size_t)b * DD + d) * LL + l0) : nullptr;
    float sum = 0.f;
    for (int j = l0 - 12; j <= l0 + 12; ++j) {
        int jc = j < 0 ? 0 : (j > 511 ? 511 : j);
        sum += __bfloat162float(p[jc * DD]) + __bfloat162float(q[jc * DD]);
    }
    for (int c8 = 0; c8 < 8; ++c8) {
        bf16x8 xv;
        #pragma unroll
        for (int j8 = 0; j8 < 8; ++j8) {
            int l = l0 + c8 * 8 + j8;
            float sv = __bfloat162float(p[l * DD]) + __bfloat162float(q[l * DD]);
            float r = sv - sum * (1.0f / 25.0f);
            __hip_bfloat16 rb = __float2bfloat16(r);
            ob[l * DD] = rb;
            if (WRITE_XT) xv[j8] = *(__bf16*)&rb;
            int lp = l + 13 > 511 ? 511 : l + 13;
            int lm = l - 12 < 0 ? 0 : l - 12;
            sum += (__bfloat162float(p[lp * DD]) + __bfloat162float(q[lp * DD]))
                 - (__bfloat162float(p[lm * DD]) + __bfloat162float(q[lm * DD]));
        }
        if (WRITE_XT) *(bf16x8*)(xtp + c8 * 8) = xv;
    }
}

// ---------------- LayerNorm over D (bf16 in, bf16 out) ----------------
__global__ void k_ln(const __hip_bfloat16* __restrict__ Xin, const float* __restrict__ lw,
                     const float* __restrict__ lb, __hip_bfloat16* __restrict__ Out) {
    int row = blockIdx.x;
    int t = threadIdx.x;  // 64
    bf16x8 xv = *(const bf16x8*)(Xin + (size_t)row * DD + t * 8);
    float x[8];
    #pragma unroll
    for (int j = 0; j < 8; ++j) x[j] = (float)xv[j];
    float s = 0.f;
    #pragma unroll
    for (int j = 0; j < 8; ++j) s += x[j];
    #pragma unroll
    for (int o = 32; o; o >>= 1) s += __shfl_down(s, o);
    float mu = __shfl(s, 0) * (1.0f / 512.0f);
    float vs = 0.f;
    #pragma unroll
    for (int j = 0; j < 8; ++j) { x[j] -= mu; vs += x[j] * x[j]; }
    #pragma unroll
    for (int o = 32; o; o >>= 1) vs += __shfl_down(vs, o);
    float var = __shfl(vs, 0) * (1.0f / 512.0f);
    float rstd = rsqrtf(var + 1e-5f);
    float4 w0 = ((const float4*)lw)[t * 2], w1 = ((const float4*)lw)[t * 2 + 1];
    float4 b0 = ((const float4*)lb)[t * 2], b1 = ((const float4*)lb)[t * 2 + 1];
    bf16x8 r;
    r[0] = (__bf16)fmaf(x[0] * rstd, w0.x, b0.x);
    r[1] = (__bf16)fmaf(x[1] * rstd, w0.y, b0.y);
    r[2] = (__bf16)fmaf(x[2] * rstd, w0.z, b0.z);
    r[3] = (__bf16)fmaf(x[3] * rstd, w0.w, b0.w);
    r[4] = (__bf16)fmaf(x[4] * rstd, w1.x, b1.x);
    r[5] = (__bf16)fmaf(x[5] * rstd, w1.y, b1.y);
    r[6] = (__bf16)fmaf(x[6] * rstd, w1.z, b1.z);
    r[7] = (__bf16)fmaf(x[7] * rstd, w1.w, b1.w);
    *(bf16x8*)(Out + (size_t)row * DD + t * 8) = r;
}

// ---------------- column (temporal) mean over L per (b,d), bf16 input --------------------
__global__ void k_colmean(const __hip_bfloat16* __restrict__ A, float* __restrict__ CM) {
    int col0 = blockIdx.x * 64;
    int part = threadIdx.x >> 6;
    int cl = threadIdx.x & 63;
    int col = col0 + cl;
    int b = col >> 9, d = col & 511;
    const __hip_bfloat16* a = A + (size_t)b * LL * DD + d;
    float s = 0.f;
    for (int l = part * 128; l < part * 128 + 128; ++l) s += __bfloat162float(a[l * DD]);
    __shared__ float red[4][64];
    red[part][cl] = s;
    __syncthreads();
    if (threadIdx.x < 64) {
        float v = red[0][cl] + red[1][cl] + red[2][cl] + red[3][cl];
        CM[col0 + cl] = v * (1.0f / 512.0f);
    }
}

// ---------------- final projection (gelu(A - CM) fused in), bf16 input -------------------
__global__ __launch_bounds__(256) void k_proj_partial(const __hip_bfloat16* __restrict__ A,
        const float* __restrict__ CM, const float* __restrict__ PW,
        float* __restrict__ PP) {
    int b = blockIdx.x, c = blockIdx.y;
    int t = threadIdx.x;
    float acc[NCC] = {};
    const __hip_bfloat16* a = A + (size_t)b * LL * DD;
    const float* cm = CM + (b << 9);
    int i0 = c * 16384, i1 = i0 + 16384;
    for (int i = i0 + t; i < i1; i += 256) {
        float v = gelu_f(__bfloat162float(a[i]) - cm[i & 511]);
        const float* w = PW + (size_t)i * NCC;
        #pragma unroll
        for (int n = 0; n < NCC; ++n) acc[n] = fmaf(v, w[n], acc[n]);
    }
    __shared__ float red[4][NCC];
    int lane = t & 63, wv = t >> 6;
    #pragma unroll
    for (int n = 0; n < NCC; ++n) {
        float s = acc[n];
        #pragma unroll
        for (int o = 32; o; o >>= 1) s += __shfl_down(s, o);
        if (lane == 0) red[wv][n] = s;
    }
    __syncthreads();
    if (t < NCC) {
        PP[(b * 16 + c) * NCC + t] = red[0][t] + red[1][t] + red[2][t] + red[3][t];
    }
}

__global__ void k_proj_final(const float* __restrict__ PP, const float* __restrict__ pb,
                             float* __restrict__ out) {
    int t = threadIdx.x;
    if (t >= BB * NCC) return;
    int b = t / NCC, n = t % NCC;
    float s = pb[n];
    for (int c = 0; c < 16; ++c) s += PP[(b * 16 + c) * NCC + n];
    out[t] = s;
}

// ---------------- numpy legacy RandomState(0) modes replication ----------------
static void compute_modes(int* out) {
    static uint32_t mt[624];
    uint32_t s = 0u;
    mt[0] = s;
    for (int i = 1; i < 624; ++i)
        mt[i] = 1812433253u * (mt[i - 1] ^ (mt[i - 1] >> 30)) + (uint32_t)i;
    int mti = 624;
    auto genrand = [&]() -> uint32_t {
        if (mti >= 624) {
            for (int k = 0; k < 624; ++k) {
                uint32_t y = (mt[k] & 0x80000000u) | (mt[(k + 1) % 624] & 0x7fffffffu);
                mt[k] = mt[(k + 397) % 624] ^ (y >> 1) ^ ((y & 1u) ? 2567483615u : 0u);
            }
            mti = 0;
        }
        uint32_t y = mt[mti++];
        y ^= y >> 11;
        y ^= (y << 7) & 2636928640u;
        y ^= (y << 15) & 4022730752u;
        y ^= y >> 18;
        return y;
    };
    int idx[256];
    for (int i = 0; i < 256; ++i) idx[i] = i;
    for (int i = 255; i >= 1; --i) {
        uint32_t mx = (uint32_t)i;
        uint32_t mask = mx;
        mask |= mask >> 1; mask |= mask >> 2; mask |= mask >> 4;
        mask |= mask >> 8; mask |= mask >> 16;
        uint32_t j;
        while ((j = (genrand() & mask)) > mx) {}
        int tmp = idx[i]; idx[i] = idx[j]; idx[j] = tmp;
    }
    int sel[NM];
    for (int i = 0; i < NM; ++i) sel[i] = idx[i];
    std::sort(sel, sel + NM);
    for (int i = 0; i < NM; ++i) out[i] = sel[i];
}

extern "C" void kernel_launch(void* const* d_in, const int* in_sizes, int n_in,
                              void* d_out, int out_size, void* d_ws, size_t ws_size,
                              hipStream_t stream) {
    const float* xe  = (const float*)d_in[0];
    const float* tw  = (const float*)d_in[1];
    const float* Wq  = (const float*)d_in[2];
    const float* bq  = (const float*)d_in[3];
    const float* Wo  = (const float*)d_in[8];
    const float* bo  = (const float*)d_in[9];
    const float* fwr = (const float*)d_in[10];
    const float* fwi = (const float*)d_in[11];
    const float* W1  = (const float*)d_in[12];
    const float* W2  = (const float*)d_in[13];
    const float* lw  = (const float*)d_in[14];
    const float* lb  = (const float*)d_in[15];
    const float* pw  = (const float*)d_in[16];
    const float* pb  = (const float*)d_in[17];
    float* out = (float*)d_out;

    const size_t NX = (size_t)BB * LL * DD;        // 8388608
    const size_t NHF = (size_t)BB * LL * NDFF;     // 33554432
    const size_t NXG = (size_t)BB * NH * EHH * NM; // 524288
    const size_t NWM = (size_t)NH * NM * EHH * EHH;// 1048576 u32 per layer

    char* wsb = (char*)d_ws;
    size_t off = 0;
    float* TB  = (float*)(wsb + off); off += NX * 4;
    float* XGr = (float*)(wsb + off); off += NXG * 4;
    float* XGi = (float*)(wsb + off); off += NXG * 4;
    __hip_bfloat16* X1b = (__hip_bfloat16*)(wsb + off); off += NX * 2;
    __hip_bfloat16* X2b = (__hip_bfloat16*)(wsb + off); off += NX * 2;
    __hip_bfloat16* HMb = (__hip_bfloat16*)(wsb + off); off += NHF * 2;
    __hip_bfloat16* WT3 = (__hip_bfloat16*)(wsb + off); off += (size_t)NEL * DD * DD * 2;
    uint32_t* WM3       = (uint32_t*)(wsb + off);       off += (size_t)NEL * NWM * 4;
    __hip_bfloat16* TXb = (__hip_bfloat16*)(wsb + off); off += (size_t)BB * 64 * 512 * 2;
    __hip_bfloat16* Tb  = (__hip_bfloat16*)(wsb + off); off += (size_t)64 * 512 * 2;
    __hip_bfloat16* OGT = (__hip_bfloat16*)(wsb + off); off += (size_t)BB * 512 * 64 * 2;
    __hip_bfloat16* Sk  = (__hip_bfloat16*)(wsb + off); off += (size_t)64 * 512 * 2;
    __hip_bfloat16* WTq = (__hip_bfloat16*)(wsb + off); off += (size_t)NEL * DD * DD * 2;
    __hip_bfloat16* WT1 = (__hip_bfloat16*)(wsb + off); off += (size_t)NEL * DD * NDFF * 2;
    __hip_bfloat16* WT2 = (__hip_bfloat16*)(wsb + off); off += (size_t)NEL * NDFF * DD * 2;
    __hip_bfloat16* SW3 = (__hip_bfloat16*)(wsb + off); off += (size_t)NEL * DD * 64 * 2;
    float* PE           = (float*)(wsb + off);          off += (size_t)LL * DD * 4;
    if (ws_size < off) return;

    // TB region (33.5 MB) aliased: XTb (bf16, first half) live from producer (embed or
    // prior decomp2) until k_tx; TBb (bf16, second half) live between k_nx/k_ffn<3> and
    // k_add_decomp. Final chain: k_ln writes LNb = XTb region (dead after last k_tx).
    __hip_bfloat16* XTb = (__hip_bfloat16*)TB;
    __hip_bfloat16* TBb = (__hip_bfloat16*)((char*)TB + NX * 2);
    __hip_bfloat16* LNb = XTb;

    Modes mi;
    compute_modes(mi.v);

    // ---- upfront (batched): tables, embedding(+XT), all weight preps ----
    k_tabs<<<640, 256, 0, stream>>>(PE, Tb, Sk, mi);
    k_embed<<<dim3(16, 2, BB), 256, 0, stream>>>(xe, tw, PE, X1b, XTb);
    k_wtall<<<7680, 256, 0, stream>>>(Wq, W1, W2, Wo, WTq, WT1, WT2, WT3);
    k_swt<<<dim3(4, NEL), 256, 0, stream>>>(Sk, WT3, SW3);
    k_wfm<<<dim3(NH * EHH, NEL), 256, 0, stream>>>(fwr, fwi, WM3);

    __hip_bfloat16* curb = X1b;
    __hip_bfloat16* altb = X2b;
    const int M = BB * LL;      // 16384

    for (int li = 0; li < NEL; ++li) {
        k_tx<<<dim3(BB, 8), 256, 0, stream>>>(Tb, XTb, TXb);
        k_xg<<<dim3(32, 8), 256, 0, stream>>>(TXb, WTq + (size_t)li * DD * DD,
                                              bq + li * DD, XGr, XGi, mi);
        k_og<<<NH * NM, 256, 0, stream>>>(XGr, XGi, WM3 + (size_t)li * NWM, OGT);
        k_nx<<<dim3(4, 4, BB), 256, 0, stream>>>(OGT, SW3 + (size_t)li * DD * 64,
                                                 bo + li * DD, TBb);
        k_add_decomp<false><<<BB * 8, DD, 0, stream>>>(curb, TBb, altb, nullptr);
        { __hip_bfloat16* t_ = curb; curb = altb; altb = t_; }
        // ---- FFN: 128x128 3-blk/CU counted-vmcnt MFMA GEMMs (32x32x16) ----
        k_ffn<1><<<dim3(M / 128, NDFF / 128), 256, 0, stream>>>(
            curb, WT1 + (size_t)li * DD * NDFF, HMb, M, NDFF, DD);
        k_ffn<3><<<dim3(M / 128, DD / 128), 256, 0, stream>>>(
            HMb, WT2 + (size_t)li * NDFF * DD, TBb, M, DD, NDFF);
        if (li < NEL - 1)
            k_add_decomp<true><<<BB * 8, DD, 0, stream>>>(curb, TBb, altb, XTb);
        else
            k_add_decomp<false><<<BB * 8, DD, 0, stream>>>(curb, TBb, altb, nullptr);
        { __hip_bfloat16* t_ = curb; curb = altb; altb = t_; }
    }

    // ---- final: LayerNorm -> temporal-mean -> fused gelu-sub projection (all bf16) ----
    k_ln<<<BB * LL, 64, 0, stream>>>(curb, lw, lb, LNb);
    float* CM = XGr;
    float* PP = XGi;
    k_colmean<<<256, 256, 0, stream>>>(LNb, CM);
    k_proj_partial<<<dim3(BB, 16), 256, 0, stream>>>(LNb, CM, pw, PP);
    k_proj_final<<<1, 320, 0, stream>>>(PP, pb, out);
}

// Round 20
// 661.948 us; speedup vs baseline: 1.0222x; 1.0222x over previous
//
#include <hip/hip_runtime.h>
#include <hip/hip_bf16.h>
#include <stdint.h>
#include <algorithm>

#define BB  32
#define LL  512
#define NCI 21
#define DD  512
#define NH  8
#define EHH 64
#define NDFF 2048
#define NM  32
#define NEL 3
#define NCC 10

struct Modes { int v[NM]; };

typedef __bf16 bf16x8 __attribute__((ext_vector_type(8)));
typedef float f32x4 __attribute__((ext_vector_type(4)));

// A&S 7.1.26 erf, |eps| <= 1.5e-7, branchless
__device__ __forceinline__ float erf_poly(float x) {
    float ax = fabsf(x);
    float t = 1.0f / fmaf(0.3275911f, ax, 1.0f);
    float y = t * fmaf(t, fmaf(t, fmaf(t, fmaf(t, 1.061405429f, -1.453152027f),
                                       1.421413741f), -0.284496736f), 0.254829592f);
    float r = 1.0f - y * __expf(-ax * ax);
    return copysignf(r, x);
}

__device__ __forceinline__ float gelu_f(float x) {
    return 0.5f * x * (1.0f + erf_poly(x * 0.7071067811865475f));
}

__device__ __forceinline__ float bf2f(uint16_t u) {
    union { uint32_t u32; float f; } c;
    c.u32 = (uint32_t)u << 16;
    return c.f;
}

__device__ __forceinline__ void gload_lds16(const void* g, void* l) {
    __builtin_amdgcn_global_load_lds((const __attribute__((address_space(1))) void*)g,
                                     (__attribute__((address_space(3))) void*)l, 16, 0, 0);
}

// ---------------- combined tables: PE (512 rows), T (64 rows), Sk (64 rows) --------------
__global__ void k_tabs(float* __restrict__ PE, __hip_bfloat16* __restrict__ Tb,
                       __hip_bfloat16* __restrict__ Sk, Modes md) {
    int bid = blockIdx.x;
    const float w0 = 6.283185307179586f / 512.0f;
    if (bid < 512) {
        int l = bid;
        for (int d = threadIdx.x; d < DD; d += 256) {
            int a = d & ~1;
            float freq = expf((float)a * (-9.210340371976184f / 512.0f));
            float v = (float)l * freq;
            PE[l * DD + d] = (d & 1) ? cosf(v) : sinf(v);
        }
    } else if (bid < 576) {
        int r = bid - 512, m = r >> 1, im = md.v[m];
        for (int l = threadIdx.x; l < LL; l += 256) {
            int red = (im * l) & 511;
            float ang = w0 * (float)red;
            Tb[r * 512 + l] = __float2bfloat16((r & 1) ? sinf(ang) : cosf(ang));
        }
    } else {
        int k = bid - 576, m = k >> 1;
        for (int l = threadIdx.x; l < LL; l += 256) {
            int red = (m * l) & 511;
            float ang = w0 * (float)red;
            float v;
            if ((k & 1) == 0) v = cosf(ang) * (m == 0 ? (1.0f / 512.0f) : (2.0f / 512.0f));
            else              v = -sinf(ang) * (2.0f / 512.0f);
            Sk[k * 512 + l] = __float2bfloat16(v);
        }
    }
}

// ---------------- embedding: conv1d(k=3, circular) + PE -> bf16 Xb AND XT[b][d][l] -------
__global__ __launch_bounds__(256) void k_embed(const float* __restrict__ xe,
        const float* __restrict__ tw, const float* __restrict__ PE,
        __hip_bfloat16* __restrict__ Xb, __hip_bfloat16* __restrict__ XT) {
    int lc = blockIdx.x, dh = blockIdx.y, b = blockIdx.z;
    int t = threadIdx.x;
    int d = dh * 256 + t;
    __shared__ float s_xe[34][NCI];
    int l0 = lc * 32;
    for (int i = t; i < 34 * NCI; i += 256) {
        int r = i / NCI, c = i % NCI;
        int ls = (l0 - 1 + r + LL) & (LL - 1);
        s_xe[r][c] = xe[(b * LL + ls) * NCI + c];
    }
    float twr[63];
    #pragma unroll
    for (int kc = 0; kc < 63; ++kc) twr[kc] = tw[kc * DD + d];
    __syncthreads();
    __hip_bfloat16* xtp = XT + ((size_t)b * DD + d) * LL + l0;
    #pragma unroll
    for (int c8 = 0; c8 < 4; ++c8) {
        bf16x8 xv;
        #pragma unroll
        for (int j = 0; j < 8; ++j) {
            int li = c8 * 8 + j;
            int l = l0 + li;
            float acc = 0.f;
            #pragma unroll
            for (int k = 0; k < 3; ++k)
                #pragma unroll
                for (int c = 0; c < NCI; ++c)
                    acc = fmaf(s_xe[li + k][c], twr[k * NCI + c], acc);
            float r = acc + PE[l * DD + d];
            __hip_bfloat16 rb = __float2bfloat16(r);
            Xb[((size_t)(b * LL + l)) * DD + d] = rb;
            xv[j] = *(__bf16*)&rb;
        }
        *(bf16x8*)(xtp + c8 * 8) = xv;
    }
}

// ---------------- ALL weight converts in one launch (1-D segment decode) -----------------
__global__ void k_wtall(const float* __restrict__ Wq, const float* __restrict__ W1,
                        const float* __restrict__ W2, const float* __restrict__ Wo,
                        __hip_bfloat16* __restrict__ WTq, __hip_bfloat16* __restrict__ WT1,
                        __hip_bfloat16* __restrict__ WT2, __hip_bfloat16* __restrict__ WT3) {
    int id = blockIdx.x;
    const float* W; __hip_bfloat16* WT; int K, N, gx, li, r;
    if (id < 768)        { li = id / 256; r = id % 256;  W = Wq; WT = WTq; K = 512;  N = 512;  gx = 16; }
    else if (id < 3840)  { id -= 768;  li = id / 1024; r = id % 1024; W = W1; WT = WT1; K = 512;  N = 2048; gx = 64; }
    else if (id < 6912)  { id -= 3840; li = id / 1024; r = id % 1024; W = W2; WT = WT2; K = 2048; N = 512;  gx = 16; }
    else                 { id -= 6912; li = id / 256;  r = id % 256;  W = Wo; WT = WT3; K = 512;  N = 512;  gx = 16; }
    int bx = r % gx, by = r / gx;
    size_t loff = (size_t)li * K * N;
    W += loff; WT += loff;
    __shared__ float s[32][33];
    int t = threadIdx.x;
    int rr = t >> 5, c = t & 31;
    #pragma unroll
    for (int i = 0; i < 4; ++i)
        s[rr + i * 8][c] = W[(size_t)(by * 32 + rr + i * 8) * N + bx * 32 + c];
    __syncthreads();
    #pragma unroll
    for (int i = 0; i < 4; ++i) {
        int n = bx * 32 + rr + i * 8;
        WT[(size_t)n * K + by * 32 + c] = __float2bfloat16(s[c][rr + i * 8]);
    }
}

// ---------------- fourier weight transpose -> packed bf16 pairs WM3[li][hm][e][o] --------
__global__ void k_wfm(const float* __restrict__ fwr, const float* __restrict__ fwi,
                      uint32_t* __restrict__ WM3) {
    int li = blockIdx.y;
    int blk = blockIdx.x;        // h*64 + e
    int h = blk >> 6, e = blk & 63;
    int t = threadIdx.x;
    __shared__ uint32_t s[32][65];
    const float* br = fwr + (((size_t)(li * NH + h) * EHH + e) * EHH) * NM;
    const float* bi = fwi + (((size_t)(li * NH + h) * EHH + e) * EHH) * NM;
    for (int i = t; i < 2048; i += 256) {
        int o = i >> 5, m = i & 31;
        union { __hip_bfloat16 h2[2]; uint32_t u; } pk;
        pk.h2[0] = __float2bfloat16(br[i]);
        pk.h2[1] = __float2bfloat16(bi[i]);
        s[m][o] = pk.u;
    }
    __syncthreads();
    uint32_t* WM = WM3 + (size_t)li * (NH * NM * EHH * EHH);
    int mr = t >> 6, o = t & 63;
    for (int m = mr; m < 32; m += 4)
        WM[((size_t)(h * 32 + m)) * 4096 + e * 64 + o] = s[m][o];
}

// ---------------- TX[b] = T[64x512] @ XT[b], 64-col tiles (256 blocks, full GPU) ---------
__global__ __launch_bounds__(256) void k_tx(const __hip_bfloat16* __restrict__ Tb,
        const __hip_bfloat16* __restrict__ XT, __hip_bfloat16* __restrict__ TX) {
    __shared__ __hip_bfloat16 Ts[64 * 32];
    __shared__ __hip_bfloat16 Xs[64 * 32];
    int b = blockIdx.x, n0 = blockIdx.y * 64;
    int t = threadIdx.x, w = t >> 6, ln = t & 63;
    const __hip_bfloat16* xb = XT + (size_t)b * DD * LL;
    int srow = t >> 2, sq = t & 3;
    f32x4 acc[4] = {};
    for (int k0 = 0; k0 < 512; k0 += 32) {
        gload_lds16(Tb + srow * 512 + k0 + sq * 8, (char*)Ts + w * 1024);
        gload_lds16(xb + (size_t)(n0 + srow) * LL + k0 + sq * 8, (char*)Xs + w * 1024);
        __syncthreads();
        int lr = ln & 15, kc = (ln >> 4) * 8;
        bf16x8 af[4], bfr;
        #pragma unroll
        for (int mi = 0; mi < 4; ++mi)
            af[mi] = *(const bf16x8*)&Ts[(mi * 16 + lr) * 32 + kc];
        bfr = *(const bf16x8*)&Xs[(w * 16 + lr) * 32 + kc];
        #pragma unroll
        for (int mi = 0; mi < 4; ++mi)
            acc[mi] = __builtin_amdgcn_mfma_f32_16x16x32_bf16(af[mi], bfr, acc[mi], 0, 0, 0);
        __syncthreads();
    }
    int rb = (ln >> 4) * 4, cb = ln & 15;
    #pragma unroll
    for (int mi = 0; mi < 4; ++mi)
        #pragma unroll
        for (int j = 0; j < 4; ++j) {
            int m = mi * 16 + rb + j;
            int col = n0 + w * 16 + cb;
            TX[(size_t)(b * 64 + m) * 512 + col] = __float2bfloat16(acc[mi][j]);
        }
}

// ---------------- SW = Sk @ WoT^T (batched layers via blockIdx.y) -> SWT[dc][k] ----------
__global__ __launch_bounds__(256) void k_swt(const __hip_bfloat16* __restrict__ Sk,
        const __hip_bfloat16* __restrict__ WT3, __hip_bfloat16* __restrict__ SW3) {
    int li = blockIdx.y;
    const __hip_bfloat16* WT = WT3 + (size_t)li * DD * DD;
    __hip_bfloat16* SWT = SW3 + (size_t)li * DD * 64;
    __shared__ __hip_bfloat16 Ts[64 * 32];
    __shared__ __hip_bfloat16 Xs[128 * 32];
    int n0 = blockIdx.x * 128;
    int t = threadIdx.x, w = t >> 6, ln = t & 63;
    f32x4 acc[4][2] = {};
    for (int k0 = 0; k0 < 512; k0 += 32) {
        {
            int row = w * 16 + (ln >> 2), q = ln & 3;
            gload_lds16(Sk + row * 512 + k0 + q * 8, (char*)Ts + w * 1024);
        }
        #pragma unroll
        for (int i = 0; i < 2; ++i) {
            int s = i * 256 + t;
            int row = s >> 2, q = s & 3;
            gload_lds16(WT + (size_t)(n0 + row) * 512 + k0 + q * 8,
                        (char*)Xs + i * 4096 + w * 1024);
        }
        __syncthreads();
        int lr = ln & 15, kc = (ln >> 4) * 8;
        bf16x8 af[4], bfr[2];
        #pragma unroll
        for (int mi = 0; mi < 4; ++mi)
            af[mi] = *(const bf16x8*)&Ts[(mi * 16 + lr) * 32 + kc];
        #pragma unroll
        for (int ni = 0; ni < 2; ++ni)
            bfr[ni] = *(const bf16x8*)&Xs[(w * 32 + ni * 16 + lr) * 32 + kc];
        #pragma unroll
        for (int mi = 0; mi < 4; ++mi)
            #pragma unroll
            for (int ni = 0; ni < 2; ++ni)
                acc[mi][ni] = __builtin_amdgcn_mfma_f32_16x16x32_bf16(
                    af[mi], bfr[ni], acc[mi][ni], 0, 0, 0);
        __syncthreads();
    }
    int rb = (ln >> 4) * 4, cb = ln & 15;
    #pragma unroll
    for (int mi = 0; mi < 4; ++mi)
        #pragma unroll
        for (int ni = 0; ni < 2; ++ni)
            #pragma unroll
            for (int j = 0; j < 4; ++j) {
                int k = mi * 16 + rb + j;
                int col = n0 + w * 32 + ni * 16 + cb;   // dc
                SWT[(size_t)col * 64 + k] = __float2bfloat16(acc[mi][ni][j]);
            }
}

// ---------------- XG = TX @ Wq, 64x64 tiles (256 blocks), scatter to [hm][e*32+b] --------
__global__ __launch_bounds__(256) void k_xg(const __hip_bfloat16* __restrict__ A,
        const __hip_bfloat16* __restrict__ Bt, const float* __restrict__ bq,
        float* __restrict__ XGr, float* __restrict__ XGi, Modes md) {
    __shared__ __hip_bfloat16 As[64 * 32];
    __shared__ __hip_bfloat16 Bs[64 * 32];
    int t = threadIdx.x;
    int m0 = blockIdx.x * 64, n0 = blockIdx.y * 64;
    int w = t >> 6, ln = t & 63;
    int wr = w >> 1, wc = w & 1;
    int srow = t >> 2, sq = t & 3;
    const int K = 512;
    f32x4 acc[2][2] = {};
    for (int k0 = 0; k0 < K; k0 += 32) {
        gload_lds16(A + (size_t)(m0 + srow) * K + k0 + sq * 8, (char*)As + w * 1024);
        gload_lds16(Bt + (size_t)(n0 + srow) * K + k0 + sq * 8, (char*)Bs + w * 1024);
        __syncthreads();
        bf16x8 af[2], bfr[2];
        int lr = ln & 15, kc = (ln >> 4) * 8;
        #pragma unroll
        for (int mi = 0; mi < 2; ++mi)
            af[mi] = *(const bf16x8*)&As[(wr * 32 + mi * 16 + lr) * 32 + kc];
        #pragma unroll
        for (int ni = 0; ni < 2; ++ni)
            bfr[ni] = *(const bf16x8*)&Bs[(wc * 32 + ni * 16 + lr) * 32 + kc];
        #pragma unroll
        for (int mi = 0; mi < 2; ++mi)
            #pragma unroll
            for (int ni = 0; ni < 2; ++ni)
                acc[mi][ni] = __builtin_amdgcn_mfma_f32_16x16x32_bf16(
                    af[mi], bfr[ni], acc[mi][ni], 0, 0, 0);
        __syncthreads();
    }
    int rb = (ln >> 4) * 4, cb = ln & 15;
    #pragma unroll
    for (int mi = 0; mi < 2; ++mi) {
        #pragma unroll
        for (int ni = 0; ni < 2; ++ni) {
            int col = n0 + wc * 32 + ni * 16 + cb;
            int h = col >> 6, e = col & 63;
            #pragma unroll
            for (int j = 0; j < 4; ++j) {
                int row = m0 + wr * 32 + mi * 16 + rb + j;
                int b = row >> 6, r = row & 63, m = r >> 1;
                float v = acc[mi][ni][j];
                int off = (h * 32 + m) * 2048 + e * 32 + b;
                if ((r & 1) == 0)
                    XGr[off] = v + (md.v[m] == 0 ? 512.f * bq[col] : 0.f);
                else
                    XGi[off] = -v;
            }
        }
    }
}

// ---------------- FFN GEMM: 128x128, BK=32, 3-buf counted-vmcnt, 3 blk/CU (R18 proven) ---
// LDS XOR swizzle s = q ^ ((row>>1)&3): free 2-way. EPI 1: gelu bf16; EPI 3: plain bf16.
template<int EPI>
__global__ __launch_bounds__(256, 3) void k_ffn(const __hip_bfloat16* __restrict__ A,
        const __hip_bfloat16* __restrict__ Bt, __hip_bfloat16* __restrict__ Cb,
        int M, int N, int K) {
    constexpr int TILE = 256 * 32;             // (128A+128B) x 32k elements = 16 KB
    __shared__ __hip_bfloat16 lds[3 * TILE];   // 48 KB -> 3 blocks/CU
    int t = threadIdx.x, w = t >> 6, ln = t & 63;
    int wr = w >> 1, wc = w & 1;
    int lr = ln & 15, q16 = ln >> 4;           // q16 in [0,4)
    int m0 = blockIdx.x * 128, n0 = blockIdx.y * 128;
    f32x4 acc[4][4] = {};
    int NT = K / 32;

    auto STAGE = [&](int buf, int kt) {
        int kb = kt * 32;
        char* ldsA = (char*)(lds + buf * TILE);    // A: 128 rows x 64 B
        char* ldsB = ldsA + 128 * 64;
        #pragma unroll
        for (int i = 0; i < 2; ++i) {
            int c = i * 256 + t;
            int row = c >> 2, q = c & 3;
            int slot = q ^ ((row >> 1) & 3);       // pre-swizzled SOURCE, linear dest
            gload_lds16(A + (size_t)(m0 + row) * K + kb + slot * 8,
                        ldsA + (i * 256 + w * 64) * 16);
        }
        #pragma unroll
        for (int i = 0; i < 2; ++i) {
            int c = i * 256 + t;
            int row = c >> 2, q = c & 3;
            int slot = q ^ ((row >> 1) & 3);
            gload_lds16(Bt + (size_t)(n0 + row) * K + kb + slot * 8,
                        ldsB + (i * 256 + w * 64) * 16);
        }
    };

    STAGE(0, 0);
    STAGE(1, 1);
    for (int kt = 0; kt < NT; ++kt) {
        if (kt + 1 < NT) asm volatile("s_waitcnt vmcnt(4)" ::: "memory");
        else             asm volatile("s_waitcnt vmcnt(0)" ::: "memory");
        __builtin_amdgcn_sched_barrier(0);
        __builtin_amdgcn_s_barrier();          // all waves: tile kt ready, kt-1 reads done
        __builtin_amdgcn_sched_barrier(0);
        if (kt + 2 < NT) STAGE((kt + 2) % 3, kt + 2);
        const __hip_bfloat16* As = lds + (kt % 3) * TILE;
        const __hip_bfloat16* Bs = As + 128 * 32;
        bf16x8 a[4], b[4];
        #pragma unroll
        for (int mi = 0; mi < 4; ++mi) {
            int row = wr * 64 + mi * 16 + lr;
            int s = q16 ^ ((row >> 1) & 3);        // swizzled READ (matches source)
            a[mi] = *(const bf16x8*)&As[row * 32 + s * 8];
        }
        #pragma unroll
        for (int ni = 0; ni < 4; ++ni) {
            int row = wc * 64 + ni * 16 + lr;
            int s = q16 ^ ((row >> 1) & 3);
            b[ni] = *(const bf16x8*)&Bs[row * 32 + s * 8];
        }
        __builtin_amdgcn_s_setprio(1);
        #pragma unroll
        for (int mi = 0; mi < 4; ++mi)
            #pragma unroll
            for (int ni = 0; ni < 4; ++ni)
                acc[mi][ni] = __builtin_amdgcn_mfma_f32_16x16x32_bf16(
                    a[mi], b[ni], acc[mi][ni], 0, 0, 0);
        __builtin_amdgcn_s_setprio(0);
    }
    int rb = q16 * 4;
    #pragma unroll
    for (int mi = 0; mi < 4; ++mi) {
        #pragma unroll
        for (int ni = 0; ni < 4; ++ni) {
            int col = n0 + wc * 64 + ni * 16 + lr;
            int rowb = m0 + wr * 64 + mi * 16 + rb;
            #pragma unroll
            for (int j = 0; j < 4; ++j) {
                float v = acc[mi][ni][j];
                size_t off = (size_t)(rowb + j) * N + col;
                if (EPI == 1) Cb[off] = __float2bfloat16(gelu_f(v));
                else Cb[off] = __float2bfloat16(v);
            }
        }
    }
}

// ---------------- og: per (h,m) complex GEMM (packed bf16 W) -> OGT[b][he][k] bf16 -------
__global__ __launch_bounds__(256) void k_og(const float* __restrict__ XGr,
        const float* __restrict__ XGi, const uint32_t* __restrict__ WM,
        __hip_bfloat16* __restrict__ OGT) {
    int hm = blockIdx.x;      // h*32+m
    int t = threadIdx.x;
    __shared__ uint32_t sw[4096];
    __shared__ float sxr[2048], sxi[2048];
    const uint32_t* w = WM + (size_t)hm * 4096;
    for (int i = t; i < 4096; i += 256) sw[i] = w[i];
    const float* xr = XGr + hm * 2048;
    const float* xi = XGi + hm * 2048;
    for (int i = t; i < 2048; i += 256) { sxr[i] = xr[i]; sxi[i] = xi[i]; }
    __syncthreads();
    int b = t >> 3, o0 = (t & 7) * 8;
    float ar[8] = {}, ai[8] = {};
    for (int e = 0; e < 64; ++e) {
        float xrv = sxr[e * 32 + b], xiv = sxi[e * 32 + b];
        #pragma unroll
        for (int j = 0; j < 8; ++j) {
            uint32_t wv = sw[e * 64 + o0 + j];
            float wrv = bf2f((uint16_t)(wv & 0xffffu));
            float wiv = bf2f((uint16_t)(wv >> 16));
            ar[j] = fmaf(xrv, wrv, fmaf(-xiv, wiv, ar[j]));
            ai[j] = fmaf(xrv, wiv, fmaf( xiv, wrv, ai[j]));
        }
    }
    int h = hm >> 5, m = hm & 31;
    __hip_bfloat16* og = OGT + (size_t)b * (512 * 64);
    #pragma unroll
    for (int j = 0; j < 8; ++j) {
        int he = h * 64 + o0 + j;
        union { __hip_bfloat16 h2[2]; uint32_t u; } pk;
        pk.h2[0] = __float2bfloat16(ar[j]);
        pk.h2[1] = __float2bfloat16(ai[j]);
        *(uint32_t*)&og[he * 64 + 2 * m] = pk.u;
    }
}

// ---------------- new_x[b][he][dc] = OGT[b](512he x 64k) @ SWT^T + bo -> bf16 ------------
__global__ __launch_bounds__(256) void k_nx(const __hip_bfloat16* __restrict__ OGT,
        const __hip_bfloat16* __restrict__ SWT, const float* __restrict__ bo,
        __hip_bfloat16* __restrict__ Cb) {
    __shared__ __hip_bfloat16 As[128 * 32];
    __shared__ __hip_bfloat16 Bs[128 * 32];
    int t = threadIdx.x;
    int m0 = blockIdx.x * 128, n0 = blockIdx.y * 128, b = blockIdx.z;
    int w = t >> 6, ln = t & 63;
    int wr = w >> 1, wc = w & 1;
    const __hip_bfloat16* ab = OGT + (size_t)b * 512 * 64;
    f32x4 acc[4][4] = {};
    for (int k0 = 0; k0 < 64; k0 += 32) {
        #pragma unroll
        for (int i = 0; i < 2; ++i) {
            int s = i * 256 + t;
            int row = s >> 2, q = s & 3;
            gload_lds16(ab + (size_t)(m0 + row) * 64 + k0 + q * 8,
                        (char*)As + i * 4096 + w * 1024);
            gload_lds16(SWT + (size_t)(n0 + row) * 64 + k0 + q * 8,
                        (char*)Bs + i * 4096 + w * 1024);
        }
        __syncthreads();
        bf16x8 af[4], bfr[4];
        int lr = ln & 15, kc = (ln >> 4) * 8;
        #pragma unroll
        for (int mi = 0; mi < 4; ++mi)
            af[mi] = *(const bf16x8*)&As[(wr * 64 + mi * 16 + lr) * 32 + kc];
        #pragma unroll
        for (int ni = 0; ni < 4; ++ni)
            bfr[ni] = *(const bf16x8*)&Bs[(wc * 64 + ni * 16 + lr) * 32 + kc];
        #pragma unroll
        for (int mi = 0; mi < 4; ++mi)
            #pragma unroll
            for (int ni = 0; ni < 4; ++ni)
                acc[mi][ni] = __builtin_amdgcn_mfma_f32_16x16x32_bf16(
                    af[mi], bfr[ni], acc[mi][ni], 0, 0, 0);
        __syncthreads();
    }
    int rb = (ln >> 4) * 4, cb = ln & 15;
    #pragma unroll
    for (int mi = 0; mi < 4; ++mi) {
        #pragma unroll
        for (int ni = 0; ni < 4; ++ni) {
            int col = n0 + wc * 64 + ni * 16 + cb;
            int he = m0 + wr * 64 + mi * 16 + rb;
            float bv = bo[col];
            #pragma unroll
            for (int j = 0; j < 4; ++j)
                Cb[((size_t)b * 512 + he + j) * 512 + col] =
                    __float2bfloat16(acc[mi][ni][j] + bv);
        }
    }
}

// ---------------- s = P + Q; out = s - movavg25(s) -> bf16 (+ optional XT write) ---------
template<bool WRITE_XT>
__global__ void k_add_decomp(const __hip_bfloat16* __restrict__ P,
                             const __hip_bfloat16* __restrict__ Q,
                             __hip_bfloat16* __restrict__ Outb,
                             __hip_bfloat16* __restrict__ XT) {
    int b = blockIdx.x >> 3;
    int l0 = (blockIdx.x & 7) * 64;
    int d = threadIdx.x;
    const __hip_bfloat16* p = P + (size_t)b * LL * DD + d;
    const __hip_bfloat16* q = Q + (size_t)b * LL * DD + d;
    __hip_bfloat16* ob = Outb + (size_t)b * LL * DD + d;
    __hip_bfloat16* xtp = WRITE_XT ? (XT + ((size_t)b * DD + d) * LL + l0) : nullptr;
    float sum = 0.f;
    for (int j = l0 - 12; j <= l0 + 12; ++j) {
        int jc = j < 0 ? 0 : (j > 511 ? 511 : j);
        sum += __bfloat162float(p[jc * DD]) + __bfloat162float(q[jc * DD]);
    }
    for (int c8 = 0; c8 < 8; ++c8) {
        bf16x8 xv;
        #pragma unroll
        for (int j8 = 0; j8 < 8; ++j8) {
            int l = l0 + c8 * 8 + j8;
            float sv = __bfloat162float(p[l * DD]) + __bfloat162float(q[l * DD]);
            float r = sv - sum * (1.0f / 25.0f);
            __hip_bfloat16 rb = __float2bfloat16(r);
            ob[l * DD] = rb;
            if (WRITE_XT) xv[j8] = *(__bf16*)&rb;
            int lp = l + 13 > 511 ? 511 : l + 13;
            int lm = l - 12 < 0 ? 0 : l - 12;
            sum += (__bfloat162float(p[lp * DD]) + __bfloat162float(q[lp * DD]))
                 - (__bfloat162float(p[lm * DD]) + __bfloat162float(q[lm * DD]));
        }
        if (WRITE_XT) *(bf16x8*)(xtp + c8 * 8) = xv;
    }
}

// ---------------- LayerNorm over D (bf16 in, bf16 out) ----------------
__global__ void k_ln(const __hip_bfloat16* __restrict__ Xin, const float* __restrict__ lw,
                     const float* __restrict__ lb, __hip_bfloat16* __restrict__ Out) {
    int row = blockIdx.x;
    int t = threadIdx.x;  // 64
    bf16x8 xv = *(const bf16x8*)(Xin + (size_t)row * DD + t * 8);
    float x[8];
    #pragma unroll
    for (int j = 0; j < 8; ++j) x[j] = (float)xv[j];
    float s = 0.f;
    #pragma unroll
    for (int j = 0; j < 8; ++j) s += x[j];
    #pragma unroll
    for (int o = 32; o; o >>= 1) s += __shfl_down(s, o);
    float mu = __shfl(s, 0) * (1.0f / 512.0f);
    float vs = 0.f;
    #pragma unroll
    for (int j = 0; j < 8; ++j) { x[j] -= mu; vs += x[j] * x[j]; }
    #pragma unroll
    for (int o = 32; o; o >>= 1) vs += __shfl_down(vs, o);
    float var = __shfl(vs, 0) * (1.0f / 512.0f);
    float rstd = rsqrtf(var + 1e-5f);
    float4 w0 = ((const float4*)lw)[t * 2], w1 = ((const float4*)lw)[t * 2 + 1];
    float4 b0 = ((const float4*)lb)[t * 2], b1 = ((const float4*)lb)[t * 2 + 1];
    bf16x8 r;
    r[0] = (__bf16)fmaf(x[0] * rstd, w0.x, b0.x);
    r[1] = (__bf16)fmaf(x[1] * rstd, w0.y, b0.y);
    r[2] = (__bf16)fmaf(x[2] * rstd, w0.z, b0.z);
    r[3] = (__bf16)fmaf(x[3] * rstd, w0.w, b0.w);
    r[4] = (__bf16)fmaf(x[4] * rstd, w1.x, b1.x);
    r[5] = (__bf16)fmaf(x[5] * rstd, w1.y, b1.y);
    r[6] = (__bf16)fmaf(x[6] * rstd, w1.z, b1.z);
    r[7] = (__bf16)fmaf(x[7] * rstd, w1.w, b1.w);
    *(bf16x8*)(Out + (size_t)row * DD + t * 8) = r;
}

// ---------------- column (temporal) mean over L per (b,d), bf16 input --------------------
__global__ void k_colmean(const __hip_bfloat16* __restrict__ A, float* __restrict__ CM) {
    int col0 = blockIdx.x * 64;
    int part = threadIdx.x >> 6;
    int cl = threadIdx.x & 63;
    int col = col0 + cl;
    int b = col >> 9, d = col & 511;
    const __hip_bfloat16* a = A + (size_t)b * LL * DD + d;
    float s = 0.f;
    for (int l = part * 128; l < part * 128 + 128; ++l) s += __bfloat162float(a[l * DD]);
    __shared__ float red[4][64];
    red[part][cl] = s;
    __syncthreads();
    if (threadIdx.x < 64) {
        float v = red[0][cl] + red[1][cl] + red[2][cl] + red[3][cl];
        CM[col0 + cl] = v * (1.0f / 512.0f);
    }
}

// ---------------- final projection (gelu(A - CM) fused in), bf16 input -------------------
__global__ __launch_bounds__(256) void k_proj_partial(const __hip_bfloat16* __restrict__ A,
        const float* __restrict__ CM, const float* __restrict__ PW,
        float* __restrict__ PP) {
    int b = blockIdx.x, c = blockIdx.y;
    int t = threadIdx.x;
    float acc[NCC] = {};
    const __hip_bfloat16* a = A + (size_t)b * LL * DD;
    const float* cm = CM + (b << 9);
    int i0 = c * 16384, i1 = i0 + 16384;
    for (int i = i0 + t; i < i1; i += 256) {
        float v = gelu_f(__bfloat162float(a[i]) - cm[i & 511]);
        const float* w = PW + (size_t)i * NCC;
        #pragma unroll
        for (int n = 0; n < NCC; ++n) acc[n] = fmaf(v, w[n], acc[n]);
    }
    __shared__ float red[4][NCC];
    int lane = t & 63, wv = t >> 6;
    #pragma unroll
    for (int n = 0; n < NCC; ++n) {
        float s = acc[n];
        #pragma unroll
        for (int o = 32; o; o >>= 1) s += __shfl_down(s, o);
        if (lane == 0) red[wv][n] = s;
    }
    __syncthreads();
    if (t < NCC) {
        PP[(b * 16 + c) * NCC + t] = red[0][t] + red[1][t] + red[2][t] + red[3][t];
    }
}

__global__ void k_proj_final(const float* __restrict__ PP, const float* __restrict__ pb,
                             float* __restrict__ out) {
    int t = threadIdx.x;
    if (t >= BB * NCC) return;
    int b = t / NCC, n = t % NCC;
    float s = pb[n];
    for (int c = 0; c < 16; ++c) s += PP[(b * 16 + c) * NCC + n];
    out[t] = s;
}

// ---------------- numpy legacy RandomState(0) modes replication ----------------
static void compute_modes(int* out) {
    static uint32_t mt[624];
    uint32_t s = 0u;
    mt[0] = s;
    for (int i = 1; i < 624; ++i)
        mt[i] = 1812433253u * (mt[i - 1] ^ (mt[i - 1] >> 30)) + (uint32_t)i;
    int mti = 624;
    auto genrand = [&]() -> uint32_t {
        if (mti >= 624) {
            for (int k = 0; k < 624; ++k) {
                uint32_t y = (mt[k] & 0x80000000u) | (mt[(k + 1) % 624] & 0x7fffffffu);
                mt[k] = mt[(k + 397) % 624] ^ (y >> 1) ^ ((y & 1u) ? 2567483615u : 0u);
            }
            mti = 0;
        }
        uint32_t y = mt[mti++];
        y ^= y >> 11;
        y ^= (y << 7) & 2636928640u;
        y ^= (y << 15) & 4022730752u;
        y ^= y >> 18;
        return y;
    };
    int idx[256];
    for (int i = 0; i < 256; ++i) idx[i] = i;
    for (int i = 255; i >= 1; --i) {
        uint32_t mx = (uint32_t)i;
        uint32_t mask = mx;
        mask |= mask >> 1; mask |= mask >> 2; mask |= mask >> 4;
        mask |= mask >> 8; mask |= mask >> 16;
        uint32_t j;
        while ((j = (genrand() & mask)) > mx) {}
        int tmp = idx[i]; idx[i] = idx[j]; idx[j] = tmp;
    }
    int sel[NM];
    for (int i = 0; i < NM; ++i) sel[i] = idx[i];
    std::sort(sel, sel + NM);
    for (int i = 0; i < NM; ++i) out[i] = sel[i];
}

extern "C" void kernel_launch(void* const* d_in, const int* in_sizes, int n_in,
                              void* d_out, int out_size, void* d_ws, size_t ws_size,
                              hipStream_t stream) {
    const float* xe  = (const float*)d_in[0];
    const float* tw  = (const float*)d_in[1];
    const float* Wq  = (const float*)d_in[2];
    const float* bq  = (const float*)d_in[3];
    const float* Wo  = (const float*)d_in[8];
    const float* bo  = (const float*)d_in[9];
    const float* fwr = (const float*)d_in[10];
    const float* fwi = (const float*)d_in[11];
    const float* W1  = (const float*)d_in[12];
    const float* W2  = (const float*)d_in[13];
    const float* lw  = (const float*)d_in[14];
    const float* lb  = (const float*)d_in[15];
    const float* pw  = (const float*)d_in[16];
    const float* pb  = (const float*)d_in[17];
    float* out = (float*)d_out;

    const size_t NX = (size_t)BB * LL * DD;        // 8388608
    const size_t NHF = (size_t)BB * LL * NDFF;     // 33554432
    const size_t NXG = (size_t)BB * NH * EHH * NM; // 524288
    const size_t NWM = (size_t)NH * NM * EHH * EHH;// 1048576 u32 per layer

    char* wsb = (char*)d_ws;
    size_t off = 0;
    float* TB  = (float*)(wsb + off); off += NX * 4;
    float* XGr = (float*)(wsb + off); off += NXG * 4;
    float* XGi = (float*)(wsb + off); off += NXG * 4;
    __hip_bfloat16* X1b = (__hip_bfloat16*)(wsb + off); off += NX * 2;
    __hip_bfloat16* X2b = (__hip_bfloat16*)(wsb + off); off += NX * 2;
    __hip_bfloat16* HMb = (__hip_bfloat16*)(wsb + off); off += NHF * 2;
    __hip_bfloat16* WT3 = (__hip_bfloat16*)(wsb + off); off += (size_t)NEL * DD * DD * 2;
    uint32_t* WM3       = (uint32_t*)(wsb + off);       off += (size_t)NEL * NWM * 4;
    __hip_bfloat16* TXb = (__hip_bfloat16*)(wsb + off); off += (size_t)BB * 64 * 512 * 2;
    __hip_bfloat16* Tb  = (__hip_bfloat16*)(wsb + off); off += (size_t)64 * 512 * 2;
    __hip_bfloat16* OGT = (__hip_bfloat16*)(wsb + off); off += (size_t)BB * 512 * 64 * 2;
    __hip_bfloat16* Sk  = (__hip_bfloat16*)(wsb + off); off += (size_t)64 * 512 * 2;
    __hip_bfloat16* WTq = (__hip_bfloat16*)(wsb + off); off += (size_t)NEL * DD * DD * 2;
    __hip_bfloat16* WT1 = (__hip_bfloat16*)(wsb + off); off += (size_t)NEL * DD * NDFF * 2;
    __hip_bfloat16* WT2 = (__hip_bfloat16*)(wsb + off); off += (size_t)NEL * NDFF * DD * 2;
    __hip_bfloat16* SW3 = (__hip_bfloat16*)(wsb + off); off += (size_t)NEL * DD * 64 * 2;
    float* PE           = (float*)(wsb + off);          off += (size_t)LL * DD * 4;
    if (ws_size < off) return;

    // TB region (33.5 MB) aliased: XTb (bf16, first half) live from producer (embed or
    // prior decomp2) until k_tx; TBb (bf16, second half) live between k_nx/k_ffn<3> and
    // k_add_decomp. Final chain: k_ln writes LNb = XTb region (dead after last k_tx).
    __hip_bfloat16* XTb = (__hip_bfloat16*)TB;
    __hip_bfloat16* TBb = (__hip_bfloat16*)((char*)TB + NX * 2);
    __hip_bfloat16* LNb = XTb;

    Modes mi;
    compute_modes(mi.v);

    // ---- upfront (batched): tables, embedding(+XT), all weight preps ----
    k_tabs<<<640, 256, 0, stream>>>(PE, Tb, Sk, mi);
    k_embed<<<dim3(16, 2, BB), 256, 0, stream>>>(xe, tw, PE, X1b, XTb);
    k_wtall<<<7680, 256, 0, stream>>>(Wq, W1, W2, Wo, WTq, WT1, WT2, WT3);
    k_swt<<<dim3(4, NEL), 256, 0, stream>>>(Sk, WT3, SW3);
    k_wfm<<<dim3(NH * EHH, NEL), 256, 0, stream>>>(fwr, fwi, WM3);

    __hip_bfloat16* curb = X1b;
    __hip_bfloat16* altb = X2b;
    const int M = BB * LL;      // 16384

    for (int li = 0; li < NEL; ++li) {
        k_tx<<<dim3(BB, 8), 256, 0, stream>>>(Tb, XTb, TXb);
        k_xg<<<dim3(32, 8), 256, 0, stream>>>(TXb, WTq + (size_t)li * DD * DD,
                                              bq + li * DD, XGr, XGi, mi);
        k_og<<<NH * NM, 256, 0, stream>>>(XGr, XGi, WM3 + (size_t)li * NWM, OGT);
        k_nx<<<dim3(4, 4, BB), 256, 0, stream>>>(OGT, SW3 + (size_t)li * DD * 64,
                                                 bo + li * DD, TBb);
        k_add_decomp<false><<<BB * 8, DD, 0, stream>>>(curb, TBb, altb, nullptr);
        { __hip_bfloat16* t_ = curb; curb = altb; altb = t_; }
        // ---- FFN: 128x128 3-blk/CU counted-vmcnt MFMA GEMMs (16x16x32, R18) ----
        k_ffn<1><<<dim3(M / 128, NDFF / 128), 256, 0, stream>>>(
            curb, WT1 + (size_t)li * DD * NDFF, HMb, M, NDFF, DD);
        k_ffn<3><<<dim3(M / 128, DD / 128), 256, 0, stream>>>(
            HMb, WT2 + (size_t)li * NDFF * DD, TBb, M, DD, NDFF);
        if (li < NEL - 1)
            k_add_decomp<true><<<BB * 8, DD, 0, stream>>>(curb, TBb, altb, XTb);
        else
            k_add_decomp<false><<<BB * 8, DD, 0, stream>>>(curb, TBb, altb, nullptr);
        { __hip_bfloat16* t_ = curb; curb = altb; altb = t_; }
    }

    // ---- final: LayerNorm -> temporal-mean -> fused gelu-sub projection (all bf16) ----
    k_ln<<<BB * LL, 64, 0, stream>>>(curb, lw, lb, LNb);
    float* CM = XGr;
    float* PP = XGi;
    k_colmean<<<256, 256, 0, stream>>>(LNb, CM);
    k_proj_partial<<<dim3(BB, 16), 256, 0, stream>>>(LNb, CM, pw, PP);
    k_proj_final<<<1, 320, 0, stream>>>(PP, pb, out);
}